// Round 1
// baseline (1485.640 us; speedup 1.0000x reference)
//
#include <hip/hip_runtime.h>

__global__ void k_deg(const int* __restrict__ dst, int E, int* __restrict__ deg) {
  int e = blockIdx.x * blockDim.x + threadIdx.x;
  if (e < E) atomicAdd(&deg[dst[e]], 1);
}

__global__ void k_dinv(const int* __restrict__ deg, float* __restrict__ dinv, int n) {
  int i = blockIdx.x * blockDim.x + threadIdx.x;
  if (i < n) dinv[i] = rsqrtf((float)(deg[i] + 1));
}

// Out[r][c] = (sum_k X[r][k] * W[k][c]) * scale[r];  X:[n][128], W:[128][128]
__global__ __launch_bounds__(256) void k_gemm_scaled(
    const float* __restrict__ X, const float* __restrict__ W,
    const float* __restrict__ scale, float* __restrict__ Out, int nrows)
{
  __shared__ float Ws[64 * 128];   // 32 KB: half of W (K-split)
  __shared__ float Xs[32 * 65];    // 8.3 KB: 32-row x 64-k tile, pad->conflict-free
  const int t = threadIdx.x;
  const int row0 = blockIdx.x * 32;
  const int c  = (t & 31) * 4;
  const int r0 = (t >> 5) * 4;
  float acc[4][4] = {{0.f,0.f,0.f,0.f},{0.f,0.f,0.f,0.f},{0.f,0.f,0.f,0.f},{0.f,0.f,0.f,0.f}};

  for (int kp = 0; kp < 2; ++kp) {
    #pragma unroll
    for (int i = 0; i < 8; ++i) {              // W half: 8192 floats
      int idx = t + i * 256;
      int wr = idx >> 5, wc4 = idx & 31;
      float4 v = ((const float4*)W)[(kp * 64 + wr) * 32 + wc4];
      *(float4*)&Ws[wr * 128 + wc4 * 4] = v;
    }
    #pragma unroll
    for (int i = 0; i < 2; ++i) {              // X tile: 2048 floats
      int idx = t + i * 256;
      int r = idx >> 4, c4 = idx & 15;
      int gr = row0 + r;
      float4 v = make_float4(0.f, 0.f, 0.f, 0.f);
      if (gr < nrows) v = ((const float4*)X)[(size_t)gr * 32 + kp * 16 + c4];
      Xs[r * 65 + c4 * 4 + 0] = v.x;
      Xs[r * 65 + c4 * 4 + 1] = v.y;
      Xs[r * 65 + c4 * 4 + 2] = v.z;
      Xs[r * 65 + c4 * 4 + 3] = v.w;
    }
    __syncthreads();
    #pragma unroll 8
    for (int k = 0; k < 64; ++k) {
      float4 w = *(const float4*)&Ws[k * 128 + c];
      float x0 = Xs[(r0 + 0) * 65 + k];
      float x1 = Xs[(r0 + 1) * 65 + k];
      float x2 = Xs[(r0 + 2) * 65 + k];
      float x3 = Xs[(r0 + 3) * 65 + k];
      acc[0][0] += x0 * w.x; acc[0][1] += x0 * w.y; acc[0][2] += x0 * w.z; acc[0][3] += x0 * w.w;
      acc[1][0] += x1 * w.x; acc[1][1] += x1 * w.y; acc[1][2] += x1 * w.z; acc[1][3] += x1 * w.w;
      acc[2][0] += x2 * w.x; acc[2][1] += x2 * w.y; acc[2][2] += x2 * w.z; acc[2][3] += x2 * w.w;
      acc[3][0] += x3 * w.x; acc[3][1] += x3 * w.y; acc[3][2] += x3 * w.z; acc[3][3] += x3 * w.w;
    }
    __syncthreads();
  }
  #pragma unroll
  for (int i = 0; i < 4; ++i) {
    int gr = row0 + r0 + i;
    if (gr < nrows) {
      float s = scale[gr];
      float4 o = make_float4(acc[i][0] * s, acc[i][1] * s, acc[i][2] * s, acc[i][3] * s);
      *(float4*)(Out + (size_t)gr * 128 + c) = o;
    }
  }
}

// agg[dst] += hs[src]  (row-wise, 64 lanes/edge, float2 per lane)
__global__ __launch_bounds__(256) void k_scatter(
    const int* __restrict__ src, const int* __restrict__ dst, int E,
    const float* __restrict__ hs, float* __restrict__ agg)
{
  int e = blockIdx.x * 4 + (threadIdx.x >> 6);
  if (e >= E) return;
  int lane = threadIdx.x & 63;
  int s = src[e], d = dst[e];
  float2 v = ((const float2*)(hs + (size_t)s * 128))[lane];
  float* a = agg + (size_t)d * 128 + lane * 2;
  atomicAdd(a, v.x);
  atomicAdd(a + 1, v.y);
}

// outbuf = relu(dinv[node] * (agg + hs) + bias)   [self-loop folded in: agg excludes it, hs IS it scaled]
__global__ __launch_bounds__(256) void k_post(
    const float* __restrict__ hs, const float* __restrict__ agg,
    const float* __restrict__ dinv, const float* __restrict__ bias,
    float* __restrict__ outbuf, int n)
{
  int idx = blockIdx.x * 256 + threadIdx.x;   // float4 index
  if (idx >= n * 32) return;
  int node = idx >> 5, c4 = idx & 31;
  float dv = dinv[node];
  float4 a = ((const float4*)agg)[idx];
  float4 h = ((const float4*)hs)[idx];
  float4 b = ((const float4*)bias)[c4];
  float4 r;
  r.x = fmaxf(dv * (a.x + h.x) + b.x, 0.f);
  r.y = fmaxf(dv * (a.y + h.y) + b.y, 0.f);
  r.z = fmaxf(dv * (a.z + h.z) + b.z, 0.f);
  r.w = fmaxf(dv * (a.w + h.w) + b.w, 0.f);
  ((float4*)outbuf)[idx] = r;
}

__device__ __forceinline__ int lower_bound_i(const int* a, int n, int v) {
  int lo = 0, hi = n;
  while (lo < hi) { int m = (lo + hi) >> 1; if (a[m] < v) lo = m + 1; else hi = m; }
  return lo;
}

// per-graph mean pool (batch is sorted) fused with the 128->128(relu)->2 MLP
__global__ __launch_bounds__(128) void k_pool_fc(
    const float* __restrict__ h2, const int* __restrict__ batch, int n,
    const float* __restrict__ Wf1, const float* __restrict__ bf1,
    const float* __restrict__ Wf2, const float* __restrict__ bf2,
    float* __restrict__ out)
{
  __shared__ float gl[128];
  __shared__ float zl[128];
  int g = blockIdx.x, t = threadIdx.x;
  int lo = lower_bound_i(batch, n, g);
  int hi = lower_bound_i(batch, n, g + 1);
  float acc = 0.f;
  for (int i = lo; i < hi; ++i) acc += h2[(size_t)i * 128 + t];
  gl[t] = acc / fmaxf((float)(hi - lo), 1.f);
  __syncthreads();
  float z = bf1[t];
  #pragma unroll 16
  for (int k = 0; k < 128; ++k) z += gl[k] * Wf1[k * 128 + t];
  zl[t] = fmaxf(z, 0.f);
  __syncthreads();
  if (t < 2) {
    float o = bf2[t];
    for (int k = 0; k < 128; ++k) o += zl[k] * Wf2[k * 2 + t];
    out[g * 2 + t] = o;
  }
}

extern "C" void kernel_launch(void* const* d_in, const int* in_sizes, int n_in,
                              void* d_out, int out_size, void* d_ws, size_t ws_size,
                              hipStream_t stream) {
  const float* x    = (const float*)d_in[0];
  const int*   ei   = (const int*)d_in[1];
  const int*   batch= (const int*)d_in[2];
  const float* W1   = (const float*)d_in[3];
  const float* b1   = (const float*)d_in[4];
  const float* W2   = (const float*)d_in[5];
  const float* b2   = (const float*)d_in[6];
  const float* Wf1  = (const float*)d_in[7];
  const float* bf1  = (const float*)d_in[8];
  const float* Wf2  = (const float*)d_in[9];
  const float* bf2  = (const float*)d_in[10];
  float* out = (float*)d_out;

  const int N  = in_sizes[0] / 128;
  const int E  = in_sizes[1] / 2;
  const int NG = out_size / 2;
  const int* srcp = ei;
  const int* dstp = ei + E;

  char* ws = (char*)d_ws;
  size_t off = 0;
  auto carve = [&](size_t bytes) { void* p = ws + off; off += (bytes + 255) & ~(size_t)255; return p; };
  int*   deg  = (int*)  carve((size_t)N * 4);
  float* dinv = (float*)carve((size_t)N * 4);
  const size_t nb_row = (size_t)N * 128 * sizeof(float);
  float* P = (float*)carve(nb_row);   // hs (scaled gemm out)
  float* Q = (float*)carve(nb_row);   // agg
  float* R = (float*)carve(nb_row);   // layer output

  hipMemsetAsync(deg, 0, (size_t)N * 4, stream);
  k_deg<<<(E + 255) / 256, 256, 0, stream>>>(dstp, E, deg);
  k_dinv<<<(N + 255) / 256, 256, 0, stream>>>(deg, dinv, N);

  // layer 1
  k_gemm_scaled<<<(N + 31) / 32, 256, 0, stream>>>(x, W1, dinv, P, N);
  hipMemsetAsync(Q, 0, nb_row, stream);
  k_scatter<<<(E + 3) / 4, 256, 0, stream>>>(srcp, dstp, E, P, Q);
  k_post<<<(N * 32 + 255) / 256, 256, 0, stream>>>(P, Q, dinv, b1, R, N);

  // layer 2
  k_gemm_scaled<<<(N + 31) / 32, 256, 0, stream>>>(R, W2, dinv, P, N);
  hipMemsetAsync(Q, 0, nb_row, stream);
  k_scatter<<<(E + 3) / 4, 256, 0, stream>>>(srcp, dstp, E, P, Q);
  k_post<<<(N * 32 + 255) / 256, 256, 0, stream>>>(P, Q, dinv, b2, R, N);

  k_pool_fc<<<NG, 128, 0, stream>>>(R, batch, N, Wf1, bf1, Wf2, bf2, out);
}

// Round 2
// 428.579 us; speedup vs baseline: 3.4664x; 3.4664x over previous
//
#include <hip/hip_runtime.h>

__global__ void k_deg(const int* __restrict__ dst, int E, int* __restrict__ deg) {
  int e = blockIdx.x * blockDim.x + threadIdx.x;
  if (e < E) atomicAdd(&deg[dst[e]], 1);
}

__global__ void k_dinv(const int* __restrict__ deg, float* __restrict__ dinv, int n) {
  int i = blockIdx.x * blockDim.x + threadIdx.x;
  if (i < n) dinv[i] = rsqrtf((float)(deg[i] + 1));
}

// single-block exclusive scan over deg -> rowptr (and cursor copy). n <= 1024*chunk
__global__ __launch_bounds__(1024) void k_scan(const int* __restrict__ deg,
                                               int* __restrict__ rowptr,
                                               int* __restrict__ cursor, int n) {
  __shared__ int sums[1024];
  int t = threadIdx.x;
  int chunk = (n + 1023) / 1024;
  int lo = t * chunk, hi = min(lo + chunk, n);
  int s = 0;
  for (int i = lo; i < hi; ++i) s += deg[i];
  sums[t] = s;
  __syncthreads();
  for (int d = 1; d < 1024; d <<= 1) {
    int v = (t >= d) ? sums[t - d] : 0;
    __syncthreads();
    sums[t] += v;
    __syncthreads();
  }
  int base = (t == 0) ? 0 : sums[t - 1];
  for (int i = lo; i < hi; ++i) {
    rowptr[i] = base;
    cursor[i] = base;
    base += deg[i];
  }
  if (t == 0) rowptr[n] = sums[1023];
}

__global__ void k_fill(const int* __restrict__ src, const int* __restrict__ dst, int E,
                       int* __restrict__ cursor, int* __restrict__ csr_src) {
  int e = blockIdx.x * blockDim.x + threadIdx.x;
  if (e < E) {
    int pos = atomicAdd(&cursor[dst[e]], 1);
    csr_src[pos] = src[e];
  }
}

// Out[r][c] = (sum_k X[r][k] * W[k][c]) * scale[r];  X:[n][128], W:[128][128]
__global__ __launch_bounds__(256) void k_gemm_scaled(
    const float* __restrict__ X, const float* __restrict__ W,
    const float* __restrict__ scale, float* __restrict__ Out, int nrows)
{
  __shared__ float Ws[64 * 128];
  __shared__ float Xs[32 * 65];
  const int t = threadIdx.x;
  const int row0 = blockIdx.x * 32;
  const int c  = (t & 31) * 4;
  const int r0 = (t >> 5) * 4;
  float acc[4][4] = {{0.f,0.f,0.f,0.f},{0.f,0.f,0.f,0.f},{0.f,0.f,0.f,0.f},{0.f,0.f,0.f,0.f}};

  for (int kp = 0; kp < 2; ++kp) {
    #pragma unroll
    for (int i = 0; i < 8; ++i) {
      int idx = t + i * 256;
      int wr = idx >> 5, wc4 = idx & 31;
      float4 v = ((const float4*)W)[(kp * 64 + wr) * 32 + wc4];
      *(float4*)&Ws[wr * 128 + wc4 * 4] = v;
    }
    #pragma unroll
    for (int i = 0; i < 2; ++i) {
      int idx = t + i * 256;
      int r = idx >> 4, c4 = idx & 15;
      int gr = row0 + r;
      float4 v = make_float4(0.f, 0.f, 0.f, 0.f);
      if (gr < nrows) v = ((const float4*)X)[(size_t)gr * 32 + kp * 16 + c4];
      Xs[r * 65 + c4 * 4 + 0] = v.x;
      Xs[r * 65 + c4 * 4 + 1] = v.y;
      Xs[r * 65 + c4 * 4 + 2] = v.z;
      Xs[r * 65 + c4 * 4 + 3] = v.w;
    }
    __syncthreads();
    #pragma unroll 8
    for (int k = 0; k < 64; ++k) {
      float4 w = *(const float4*)&Ws[k * 128 + c];
      float x0 = Xs[(r0 + 0) * 65 + k];
      float x1 = Xs[(r0 + 1) * 65 + k];
      float x2 = Xs[(r0 + 2) * 65 + k];
      float x3 = Xs[(r0 + 3) * 65 + k];
      acc[0][0] += x0 * w.x; acc[0][1] += x0 * w.y; acc[0][2] += x0 * w.z; acc[0][3] += x0 * w.w;
      acc[1][0] += x1 * w.x; acc[1][1] += x1 * w.y; acc[1][2] += x1 * w.z; acc[1][3] += x1 * w.w;
      acc[2][0] += x2 * w.x; acc[2][1] += x2 * w.y; acc[2][2] += x2 * w.z; acc[2][3] += x2 * w.w;
      acc[3][0] += x3 * w.x; acc[3][1] += x3 * w.y; acc[3][2] += x3 * w.z; acc[3][3] += x3 * w.w;
    }
    __syncthreads();
  }
  #pragma unroll
  for (int i = 0; i < 4; ++i) {
    int gr = row0 + r0 + i;
    if (gr < nrows) {
      float s = scale[gr];
      float4 o = make_float4(acc[i][0] * s, acc[i][1] * s, acc[i][2] * s, acc[i][3] * s);
      *(float4*)(Out + (size_t)gr * 128 + c) = o;
    }
  }
}

// one wave per dst node: acc = sum_{s in CSR[dst]} P[s]; R = relu(dinv*(acc + P[dst]) + b)
__global__ __launch_bounds__(256) void k_gather_post(
    const int* __restrict__ csr_src, const int* __restrict__ rowptr,
    const float* __restrict__ P, const float* __restrict__ dinv,
    const float* __restrict__ bias, float* __restrict__ R, int n)
{
  int node = blockIdx.x * 4 + (threadIdx.x >> 6);
  if (node >= n) return;
  int lane = threadIdx.x & 63;
  int lo = rowptr[node], hi = rowptr[node + 1];
  float accx = 0.f, accy = 0.f;
  #pragma unroll 4
  for (int e = lo; e < hi; ++e) {
    int s = csr_src[e];
    float2 v = ((const float2*)(P + (size_t)s * 128))[lane];
    accx += v.x; accy += v.y;
  }
  float dv = dinv[node];
  float2 h = ((const float2*)(P + (size_t)node * 128))[lane];
  float2 b = ((const float2*)bias)[lane];
  float2 r;
  r.x = fmaxf(dv * (accx + h.x) + b.x, 0.f);
  r.y = fmaxf(dv * (accy + h.y) + b.y, 0.f);
  ((float2*)(R + (size_t)node * 128))[lane] = r;
}

__device__ __forceinline__ int lower_bound_i(const int* a, int n, int v) {
  int lo = 0, hi = n;
  while (lo < hi) { int m = (lo + hi) >> 1; if (a[m] < v) lo = m + 1; else hi = m; }
  return lo;
}

__global__ __launch_bounds__(128) void k_pool_fc(
    const float* __restrict__ h2, const int* __restrict__ batch, int n,
    const float* __restrict__ Wf1, const float* __restrict__ bf1,
    const float* __restrict__ Wf2, const float* __restrict__ bf2,
    float* __restrict__ out)
{
  __shared__ float gl[128];
  __shared__ float zl[128];
  int g = blockIdx.x, t = threadIdx.x;
  int lo = lower_bound_i(batch, n, g);
  int hi = lower_bound_i(batch, n, g + 1);
  float acc = 0.f;
  for (int i = lo; i < hi; ++i) acc += h2[(size_t)i * 128 + t];
  gl[t] = acc / fmaxf((float)(hi - lo), 1.f);
  __syncthreads();
  float z = bf1[t];
  #pragma unroll 16
  for (int k = 0; k < 128; ++k) z += gl[k] * Wf1[k * 128 + t];
  zl[t] = fmaxf(z, 0.f);
  __syncthreads();
  if (t < 2) {
    float o = bf2[t];
    for (int k = 0; k < 128; ++k) o += zl[k] * Wf2[k * 2 + t];
    out[g * 2 + t] = o;
  }
}

extern "C" void kernel_launch(void* const* d_in, const int* in_sizes, int n_in,
                              void* d_out, int out_size, void* d_ws, size_t ws_size,
                              hipStream_t stream) {
  const float* x    = (const float*)d_in[0];
  const int*   ei   = (const int*)d_in[1];
  const int*   batch= (const int*)d_in[2];
  const float* W1   = (const float*)d_in[3];
  const float* b1   = (const float*)d_in[4];
  const float* W2   = (const float*)d_in[5];
  const float* b2   = (const float*)d_in[6];
  const float* Wf1  = (const float*)d_in[7];
  const float* bf1  = (const float*)d_in[8];
  const float* Wf2  = (const float*)d_in[9];
  const float* bf2  = (const float*)d_in[10];
  float* out = (float*)d_out;

  const int N  = in_sizes[0] / 128;
  const int E  = in_sizes[1] / 2;
  const int NG = out_size / 2;
  const int* srcp = ei;
  const int* dstp = ei + E;

  char* ws = (char*)d_ws;
  size_t off = 0;
  auto carve = [&](size_t bytes) { void* p = ws + off; off += (bytes + 255) & ~(size_t)255; return p; };
  int*   deg    = (int*)  carve((size_t)N * 4);
  float* dinv   = (float*)carve((size_t)N * 4);
  int*   rowptr = (int*)  carve((size_t)(N + 1) * 4);
  int*   cursor = (int*)  carve((size_t)N * 4);
  int*   csr    = (int*)  carve((size_t)E * 4);
  const size_t nb_row = (size_t)N * 128 * sizeof(float);
  float* P = (float*)carve(nb_row);   // scaled gemm out
  float* R = (float*)carve(nb_row);   // layer output

  hipMemsetAsync(deg, 0, (size_t)N * 4, stream);
  k_deg<<<(E + 255) / 256, 256, 0, stream>>>(dstp, E, deg);
  k_dinv<<<(N + 255) / 256, 256, 0, stream>>>(deg, dinv, N);
  k_scan<<<1, 1024, 0, stream>>>(deg, rowptr, cursor, N);
  k_fill<<<(E + 255) / 256, 256, 0, stream>>>(srcp, dstp, E, cursor, csr);

  // layer 1
  k_gemm_scaled<<<(N + 31) / 32, 256, 0, stream>>>(x, W1, dinv, P, N);
  k_gather_post<<<(N + 3) / 4, 256, 0, stream>>>(csr, rowptr, P, dinv, b1, R, N);

  // layer 2
  k_gemm_scaled<<<(N + 31) / 32, 256, 0, stream>>>(R, W2, dinv, P, N);
  k_gather_post<<<(N + 3) / 4, 256, 0, stream>>>(csr, rowptr, P, dinv, b2, R, N);

  k_pool_fc<<<NG, 128, 0, stream>>>(R, batch, N, Wf1, bf1, Wf2, bf2, out);
}

// Round 3
// 326.504 us; speedup vs baseline: 4.5501x; 1.3126x over previous
//
#include <hip/hip_runtime.h>

__global__ void k_deg(const int* __restrict__ dst, int E, int* __restrict__ deg) {
  int e = blockIdx.x * blockDim.x + threadIdx.x;
  if (e < E) atomicAdd(&deg[dst[e]], 1);
}

// phase 1: per-block inclusive scan of deg; writes intra-block EXCLUSIVE value,
// per-block sum, and (fused) dinv = rsqrt(deg+1)
__global__ __launch_bounds__(1024) void k_scan1(
    const int* __restrict__ deg, int* __restrict__ excl,
    int* __restrict__ partials, float* __restrict__ dinv, int n)
{
  __shared__ int s[1024];
  int t = threadIdx.x;
  int i = blockIdx.x * 1024 + t;
  int v = (i < n) ? deg[i] : 0;
  if (i < n) dinv[i] = rsqrtf((float)(v + 1));
  s[t] = v;
  __syncthreads();
  #pragma unroll
  for (int d = 1; d < 1024; d <<= 1) {
    int u = (t >= d) ? s[t - d] : 0;
    __syncthreads();
    s[t] += u;
    __syncthreads();
  }
  if (i < n) excl[i] = s[t] - v;
  if (t == 1023) partials[blockIdx.x] = s[t];
}

// phase 2: single-block exclusive scan of nb (<=1024) partials, in place;
// writes rowptr[n] = grand total
__global__ __launch_bounds__(1024) void k_scan2(int* __restrict__ partials, int nb,
                                                int* __restrict__ rowptr, int n) {
  __shared__ int s[1024];
  int t = threadIdx.x;
  int v = (t < nb) ? partials[t] : 0;
  s[t] = v;
  __syncthreads();
  #pragma unroll
  for (int d = 1; d < 1024; d <<= 1) {
    int u = (t >= d) ? s[t - d] : 0;
    __syncthreads();
    s[t] += u;
    __syncthreads();
  }
  if (t < nb) partials[t] = s[t] - v;   // exclusive
  if (t == 0) rowptr[n] = s[1023];      // total edge count
}

// phase 3: rowptr/cursor = intra-block excl + block base
__global__ void k_scan3(const int* __restrict__ excl, const int* __restrict__ partials,
                        int* __restrict__ rowptr, int* __restrict__ cursor, int n) {
  int i = blockIdx.x * blockDim.x + threadIdx.x;
  if (i < n) {
    int r = excl[i] + partials[i >> 10];
    rowptr[i] = r;
    cursor[i] = r;
  }
}

__global__ void k_fill(const int* __restrict__ src, const int* __restrict__ dst, int E,
                       int* __restrict__ cursor, int* __restrict__ csr_src) {
  int e = blockIdx.x * blockDim.x + threadIdx.x;
  if (e < E) {
    int pos = atomicAdd(&cursor[dst[e]], 1);
    csr_src[pos] = src[e];
  }
}

// Out[r][c] = (sum_k X[r][k] * W[k][c]) * scale[r];  X:[n][128], W:[128][128]
__global__ __launch_bounds__(256) void k_gemm_scaled(
    const float* __restrict__ X, const float* __restrict__ W,
    const float* __restrict__ scale, float* __restrict__ Out, int nrows)
{
  __shared__ float Ws[64 * 128];
  __shared__ float Xs[32 * 65];
  const int t = threadIdx.x;
  const int row0 = blockIdx.x * 32;
  const int c  = (t & 31) * 4;
  const int r0 = (t >> 5) * 4;
  float acc[4][4] = {{0.f,0.f,0.f,0.f},{0.f,0.f,0.f,0.f},{0.f,0.f,0.f,0.f},{0.f,0.f,0.f,0.f}};

  for (int kp = 0; kp < 2; ++kp) {
    #pragma unroll
    for (int i = 0; i < 8; ++i) {
      int idx = t + i * 256;
      int wr = idx >> 5, wc4 = idx & 31;
      float4 v = ((const float4*)W)[(kp * 64 + wr) * 32 + wc4];
      *(float4*)&Ws[wr * 128 + wc4 * 4] = v;
    }
    #pragma unroll
    for (int i = 0; i < 2; ++i) {
      int idx = t + i * 256;
      int r = idx >> 4, c4 = idx & 15;
      int gr = row0 + r;
      float4 v = make_float4(0.f, 0.f, 0.f, 0.f);
      if (gr < nrows) v = ((const float4*)X)[(size_t)gr * 32 + kp * 16 + c4];
      Xs[r * 65 + c4 * 4 + 0] = v.x;
      Xs[r * 65 + c4 * 4 + 1] = v.y;
      Xs[r * 65 + c4 * 4 + 2] = v.z;
      Xs[r * 65 + c4 * 4 + 3] = v.w;
    }
    __syncthreads();
    #pragma unroll 8
    for (int k = 0; k < 64; ++k) {
      float4 w = *(const float4*)&Ws[k * 128 + c];
      float x0 = Xs[(r0 + 0) * 65 + k];
      float x1 = Xs[(r0 + 1) * 65 + k];
      float x2 = Xs[(r0 + 2) * 65 + k];
      float x3 = Xs[(r0 + 3) * 65 + k];
      acc[0][0] += x0 * w.x; acc[0][1] += x0 * w.y; acc[0][2] += x0 * w.z; acc[0][3] += x0 * w.w;
      acc[1][0] += x1 * w.x; acc[1][1] += x1 * w.y; acc[1][2] += x1 * w.z; acc[1][3] += x1 * w.w;
      acc[2][0] += x2 * w.x; acc[2][1] += x2 * w.y; acc[2][2] += x2 * w.z; acc[2][3] += x2 * w.w;
      acc[3][0] += x3 * w.x; acc[3][1] += x3 * w.y; acc[3][2] += x3 * w.z; acc[3][3] += x3 * w.w;
    }
    __syncthreads();
  }
  #pragma unroll
  for (int i = 0; i < 4; ++i) {
    int gr = row0 + r0 + i;
    if (gr < nrows) {
      float s = scale[gr];
      float4 o = make_float4(acc[i][0] * s, acc[i][1] * s, acc[i][2] * s, acc[i][3] * s);
      *(float4*)(Out + (size_t)gr * 128 + c) = o;
    }
  }
}

// one wave per dst node: acc = sum_{s in CSR[dst]} P[s]; R = relu(dinv*(acc + P[dst]) + b)
__global__ __launch_bounds__(256) void k_gather_post(
    const int* __restrict__ csr_src, const int* __restrict__ rowptr,
    const float* __restrict__ P, const float* __restrict__ dinv,
    const float* __restrict__ bias, float* __restrict__ R, int n)
{
  int node = blockIdx.x * 4 + (threadIdx.x >> 6);
  if (node >= n) return;
  int lane = threadIdx.x & 63;
  int lo = rowptr[node], hi = rowptr[node + 1];
  float accx = 0.f, accy = 0.f;
  #pragma unroll 4
  for (int e = lo; e < hi; ++e) {
    int s = csr_src[e];
    float2 v = ((const float2*)(P + (size_t)s * 128))[lane];
    accx += v.x; accy += v.y;
  }
  float dv = dinv[node];
  float2 h = ((const float2*)(P + (size_t)node * 128))[lane];
  float2 b = ((const float2*)bias)[lane];
  float2 r;
  r.x = fmaxf(dv * (accx + h.x) + b.x, 0.f);
  r.y = fmaxf(dv * (accy + h.y) + b.y, 0.f);
  ((float2*)(R + (size_t)node * 128))[lane] = r;
}

__device__ __forceinline__ int lower_bound_i(const int* a, int n, int v) {
  int lo = 0, hi = n;
  while (lo < hi) { int m = (lo + hi) >> 1; if (a[m] < v) lo = m + 1; else hi = m; }
  return lo;
}

__global__ __launch_bounds__(128) void k_pool_fc(
    const float* __restrict__ h2, const int* __restrict__ batch, int n,
    const float* __restrict__ Wf1, const float* __restrict__ bf1,
    const float* __restrict__ Wf2, const float* __restrict__ bf2,
    float* __restrict__ out)
{
  __shared__ float gl[128];
  __shared__ float zl[128];
  int g = blockIdx.x, t = threadIdx.x;
  int lo = lower_bound_i(batch, n, g);
  int hi = lower_bound_i(batch, n, g + 1);
  float acc = 0.f;
  for (int i = lo; i < hi; ++i) acc += h2[(size_t)i * 128 + t];
  gl[t] = acc / fmaxf((float)(hi - lo), 1.f);
  __syncthreads();
  float z = bf1[t];
  #pragma unroll 16
  for (int k = 0; k < 128; ++k) z += gl[k] * Wf1[k * 128 + t];
  zl[t] = fmaxf(z, 0.f);
  __syncthreads();
  if (t < 2) {
    float o = bf2[t];
    for (int k = 0; k < 128; ++k) o += zl[k] * Wf2[k * 2 + t];
    out[g * 2 + t] = o;
  }
}

extern "C" void kernel_launch(void* const* d_in, const int* in_sizes, int n_in,
                              void* d_out, int out_size, void* d_ws, size_t ws_size,
                              hipStream_t stream) {
  const float* x    = (const float*)d_in[0];
  const int*   ei   = (const int*)d_in[1];
  const int*   batch= (const int*)d_in[2];
  const float* W1   = (const float*)d_in[3];
  const float* b1   = (const float*)d_in[4];
  const float* W2   = (const float*)d_in[5];
  const float* b2   = (const float*)d_in[6];
  const float* Wf1  = (const float*)d_in[7];
  const float* bf1  = (const float*)d_in[8];
  const float* Wf2  = (const float*)d_in[9];
  const float* bf2  = (const float*)d_in[10];
  float* out = (float*)d_out;

  const int N  = in_sizes[0] / 128;
  const int E  = in_sizes[1] / 2;
  const int NG = out_size / 2;
  const int* srcp = ei;
  const int* dstp = ei + E;

  char* ws = (char*)d_ws;
  size_t off = 0;
  auto carve = [&](size_t bytes) { void* p = ws + off; off += (bytes + 255) & ~(size_t)255; return p; };
  int*   deg    = (int*)  carve((size_t)N * 4);
  float* dinv   = (float*)carve((size_t)N * 4);
  int*   excl   = (int*)  carve((size_t)N * 4);
  int*   partials=(int*)  carve((size_t)1024 * 4);
  int*   rowptr = (int*)  carve((size_t)(N + 1) * 4);
  int*   cursor = (int*)  carve((size_t)N * 4);
  int*   csr    = (int*)  carve((size_t)E * 4);
  const size_t nb_row = (size_t)N * 128 * sizeof(float);
  float* P = (float*)carve(nb_row);   // scaled gemm out
  float* R = (float*)carve(nb_row);   // layer output

  const int nb = (N + 1023) / 1024;   // <= 1024

  hipMemsetAsync(deg, 0, (size_t)N * 4, stream);
  k_deg<<<(E + 255) / 256, 256, 0, stream>>>(dstp, E, deg);
  k_scan1<<<nb, 1024, 0, stream>>>(deg, excl, partials, dinv, N);
  k_scan2<<<1, 1024, 0, stream>>>(partials, nb, rowptr, N);
  k_scan3<<<(N + 255) / 256, 256, 0, stream>>>(excl, partials, rowptr, cursor, N);
  k_fill<<<(E + 255) / 256, 256, 0, stream>>>(srcp, dstp, E, cursor, csr);

  // layer 1
  k_gemm_scaled<<<(N + 31) / 32, 256, 0, stream>>>(x, W1, dinv, P, N);
  k_gather_post<<<(N + 3) / 4, 256, 0, stream>>>(csr, rowptr, P, dinv, b1, R, N);

  // layer 2
  k_gemm_scaled<<<(N + 31) / 32, 256, 0, stream>>>(R, W2, dinv, P, N);
  k_gather_post<<<(N + 3) / 4, 256, 0, stream>>>(csr, rowptr, P, dinv, b2, R, N);

  k_pool_fc<<<NG, 128, 0, stream>>>(R, batch, N, Wf1, bf1, Wf2, bf2, out);
}

// Round 4
// 272.284 us; speedup vs baseline: 5.4562x; 1.1991x over previous
//
#include <hip/hip_runtime.h>

typedef __attribute__((ext_vector_type(8))) short short8;
typedef __attribute__((ext_vector_type(4))) float f32x4;

__device__ __forceinline__ unsigned short f2b(float x) {
  unsigned u = __float_as_uint(x);
  u += 0x7FFF + ((u >> 16) & 1);           // round-to-nearest-even
  return (unsigned short)(u >> 16);
}
__device__ __forceinline__ float b2f_lo(unsigned v) { return __uint_as_float(v << 16); }
__device__ __forceinline__ float b2f_hi(unsigned v) { return __uint_as_float(v & 0xFFFF0000u); }
__device__ __forceinline__ float b2f(unsigned short v) { return __uint_as_float(((unsigned)v) << 16); }

__global__ void k_deg(const int* __restrict__ dst, int E, int* __restrict__ deg) {
  int e = blockIdx.x * blockDim.x + threadIdx.x;
  if (e < E) atomicAdd(&deg[dst[e]], 1);
}

// phase 1: per-block inclusive scan of deg; intra-block EXCLUSIVE value, block sum, fused dinv
__global__ __launch_bounds__(1024) void k_scan1(
    const int* __restrict__ deg, int* __restrict__ excl,
    int* __restrict__ partials, float* __restrict__ dinv, int n)
{
  __shared__ int s[1024];
  int t = threadIdx.x;
  int i = blockIdx.x * 1024 + t;
  int v = (i < n) ? deg[i] : 0;
  if (i < n) dinv[i] = rsqrtf((float)(v + 1));
  s[t] = v;
  __syncthreads();
  #pragma unroll
  for (int d = 1; d < 1024; d <<= 1) {
    int u = (t >= d) ? s[t - d] : 0;
    __syncthreads();
    s[t] += u;
    __syncthreads();
  }
  if (i < n) excl[i] = s[t] - v;
  if (t == 1023) partials[blockIdx.x] = s[t];
}

__global__ __launch_bounds__(1024) void k_scan2(int* __restrict__ partials, int nb,
                                                int* __restrict__ rowptr, int n) {
  __shared__ int s[1024];
  int t = threadIdx.x;
  int v = (t < nb) ? partials[t] : 0;
  s[t] = v;
  __syncthreads();
  #pragma unroll
  for (int d = 1; d < 1024; d <<= 1) {
    int u = (t >= d) ? s[t - d] : 0;
    __syncthreads();
    s[t] += u;
    __syncthreads();
  }
  if (t < nb) partials[t] = s[t] - v;
  if (t == 0) rowptr[n] = s[1023];
}

__global__ void k_scan3(const int* __restrict__ excl, const int* __restrict__ partials,
                        int* __restrict__ rowptr, int* __restrict__ cursor, int n) {
  int i = blockIdx.x * blockDim.x + threadIdx.x;
  if (i < n) {
    int r = excl[i] + partials[i >> 10];
    rowptr[i] = r;
    cursor[i] = r;
  }
}

__global__ void k_fill(const int* __restrict__ src, const int* __restrict__ dst, int E,
                       int* __restrict__ cursor, int* __restrict__ csr_src) {
  int e = blockIdx.x * blockDim.x + threadIdx.x;
  if (e < E) {
    int pos = atomicAdd(&cursor[dst[e]], 1);
    csr_src[pos] = src[e];
  }
}

// cast + transpose W[128][128] f32 -> Wt[col][k] bf16 (so B-frags are K-contiguous)
__global__ __launch_bounds__(256) void k_prepW(const float* __restrict__ W,
                                               unsigned short* __restrict__ Wt) {
  __shared__ float t[32][33];
  int tx = threadIdx.x & 31, ty = threadIdx.x >> 5;
  int bx = blockIdx.x & 3, by = blockIdx.x >> 2;
  #pragma unroll
  for (int i = 0; i < 4; ++i)
    t[ty + i * 8][tx] = W[(by * 32 + ty + i * 8) * 128 + bx * 32 + tx];
  __syncthreads();
  #pragma unroll
  for (int i = 0; i < 4; ++i)
    Wt[(bx * 32 + ty + i * 8) * 128 + by * 32 + tx] = f2b(t[tx][ty + i * 8]);
}

// Out[r][c] = bf16( (sum_k A[r][k]*W[k][c]) * dinv[r] ).  A: f32 (A_F32=1) or bf16.
// wave handles 16 rows x 128 cols via 8 col-tiles of mfma_f32_16x16x32_bf16.
template<int A_F32>
__global__ __launch_bounds__(256) void k_mfma_gemm(
    const void* __restrict__ Ap, const unsigned short* __restrict__ Wt,
    const float* __restrict__ dinv, unsigned short* __restrict__ Out, int M)
{
  int wv = threadIdx.x >> 6, lane = threadIdx.x & 63;
  int r0 = blockIdx.x * 64 + wv * 16;
  if (r0 >= M) return;
  int arow = r0 + (lane & 15);
  int kb = (lane >> 4) * 8;
  short8 a[4];
  if (A_F32) {
    const float* Ar = (const float*)Ap + (size_t)arow * 128 + kb;
    #pragma unroll
    for (int ks = 0; ks < 4; ++ks) {
      float4 u = *(const float4*)(Ar + ks * 32);
      float4 v = *(const float4*)(Ar + ks * 32 + 4);
      short8 tt;
      tt[0] = (short)f2b(u.x); tt[1] = (short)f2b(u.y);
      tt[2] = (short)f2b(u.z); tt[3] = (short)f2b(u.w);
      tt[4] = (short)f2b(v.x); tt[5] = (short)f2b(v.y);
      tt[6] = (short)f2b(v.z); tt[7] = (short)f2b(v.w);
      a[ks] = tt;
    }
  } else {
    const unsigned short* Ar = (const unsigned short*)Ap + (size_t)arow * 128 + kb;
    #pragma unroll
    for (int ks = 0; ks < 4; ++ks)
      a[ks] = *(const short8*)(Ar + ks * 32);
  }
  f32x4 acc[8];
  #pragma unroll
  for (int i = 0; i < 8; ++i) acc[i] = (f32x4){0.f, 0.f, 0.f, 0.f};
  const unsigned short* Bc = Wt + (size_t)(lane & 15) * 128 + kb;
  #pragma unroll
  for (int ct = 0; ct < 8; ++ct) {
    const unsigned short* B = Bc + ct * 16 * 128;
    #pragma unroll
    for (int ks = 0; ks < 4; ++ks)
      acc[ct] = __builtin_amdgcn_mfma_f32_16x16x32_bf16(
          a[ks], *(const short8*)(B + ks * 32), acc[ct], 0, 0, 0);
  }
  int orow = r0 + (lane >> 4) * 4;
  int ocol = lane & 15;
  float s0 = dinv[orow], s1 = dinv[orow + 1], s2 = dinv[orow + 2], s3 = dinv[orow + 3];
  #pragma unroll
  for (int ct = 0; ct < 8; ++ct) {
    unsigned short* o = Out + (size_t)orow * 128 + ct * 16 + ocol;
    o[0]   = f2b(acc[ct][0] * s0);
    o[128] = f2b(acc[ct][1] * s1);
    o[256] = f2b(acc[ct][2] * s2);
    o[384] = f2b(acc[ct][3] * s3);
  }
}

// one wave per dst node over bf16 rows: R = bf16(relu(dinv*(sum P[src] + P[dst]) + b))
__global__ __launch_bounds__(256) void k_gather_post(
    const int* __restrict__ csr_src, const int* __restrict__ rowptr,
    const unsigned short* __restrict__ P, const float* __restrict__ dinv,
    const float* __restrict__ bias, unsigned short* __restrict__ R, int n)
{
  int node = blockIdx.x * 4 + (threadIdx.x >> 6);
  if (node >= n) return;
  int lane = threadIdx.x & 63;
  int lo = rowptr[node], hi = rowptr[node + 1];
  float ax = 0.f, ay = 0.f;
  #pragma unroll 4
  for (int e = lo; e < hi; ++e) {
    int s = csr_src[e];
    unsigned v = ((const unsigned*)(P + (size_t)s * 128))[lane];
    ax += b2f_lo(v); ay += b2f_hi(v);
  }
  float dv = dinv[node];
  unsigned hv = ((const unsigned*)(P + (size_t)node * 128))[lane];
  float2 b = ((const float2*)bias)[lane];
  float rx = fmaxf(dv * (ax + b2f_lo(hv)) + b.x, 0.f);
  float ry = fmaxf(dv * (ay + b2f_hi(hv)) + b.y, 0.f);
  unsigned pack = (unsigned)f2b(rx) | ((unsigned)f2b(ry) << 16);
  ((unsigned*)(R + (size_t)node * 128))[lane] = pack;
}

__device__ __forceinline__ int lower_bound_i(const int* a, int n, int v) {
  int lo = 0, hi = n;
  while (lo < hi) { int m = (lo + hi) >> 1; if (a[m] < v) lo = m + 1; else hi = m; }
  return lo;
}

__global__ __launch_bounds__(128) void k_pool_fc(
    const unsigned short* __restrict__ h2, const int* __restrict__ batch, int n,
    const float* __restrict__ Wf1, const float* __restrict__ bf1,
    const float* __restrict__ Wf2, const float* __restrict__ bf2,
    float* __restrict__ out)
{
  __shared__ float gl[128];
  __shared__ float zl[128];
  int g = blockIdx.x, t = threadIdx.x;
  int lo = lower_bound_i(batch, n, g);
  int hi = lower_bound_i(batch, n, g + 1);
  float acc = 0.f;
  for (int i = lo; i < hi; ++i) acc += b2f(h2[(size_t)i * 128 + t]);
  gl[t] = acc / fmaxf((float)(hi - lo), 1.f);
  __syncthreads();
  float z = bf1[t];
  #pragma unroll 16
  for (int k = 0; k < 128; ++k) z += gl[k] * Wf1[k * 128 + t];
  zl[t] = fmaxf(z, 0.f);
  __syncthreads();
  if (t < 2) {
    float o = bf2[t];
    for (int k = 0; k < 128; ++k) o += zl[k] * Wf2[k * 2 + t];
    out[g * 2 + t] = o;
  }
}

extern "C" void kernel_launch(void* const* d_in, const int* in_sizes, int n_in,
                              void* d_out, int out_size, void* d_ws, size_t ws_size,
                              hipStream_t stream) {
  const float* x    = (const float*)d_in[0];
  const int*   ei   = (const int*)d_in[1];
  const int*   batch= (const int*)d_in[2];
  const float* W1   = (const float*)d_in[3];
  const float* b1   = (const float*)d_in[4];
  const float* W2   = (const float*)d_in[5];
  const float* b2   = (const float*)d_in[6];
  const float* Wf1  = (const float*)d_in[7];
  const float* bf1  = (const float*)d_in[8];
  const float* Wf2  = (const float*)d_in[9];
  const float* bf2  = (const float*)d_in[10];
  float* out = (float*)d_out;

  const int N  = in_sizes[0] / 128;
  const int E  = in_sizes[1] / 2;
  const int NG = out_size / 2;
  const int* srcp = ei;
  const int* dstp = ei + E;

  char* ws = (char*)d_ws;
  size_t off = 0;
  auto carve = [&](size_t bytes) { void* p = ws + off; off += (bytes + 255) & ~(size_t)255; return p; };
  int*   deg    = (int*)  carve((size_t)N * 4);
  float* dinv   = (float*)carve((size_t)N * 4);
  int*   excl   = (int*)  carve((size_t)N * 4);
  int*   partials=(int*)  carve((size_t)1024 * 4);
  int*   rowptr = (int*)  carve((size_t)(N + 1) * 4);
  int*   cursor = (int*)  carve((size_t)N * 4);
  int*   csr    = (int*)  carve((size_t)E * 4);
  unsigned short* Wt1 = (unsigned short*)carve(128 * 128 * 2);
  unsigned short* Wt2 = (unsigned short*)carve(128 * 128 * 2);
  const size_t nb_row = (size_t)N * 128 * 2;   // bf16 rows
  unsigned short* U0 = (unsigned short*)carve(nb_row);
  unsigned short* U1 = (unsigned short*)carve(nb_row);

  const int nb = (N + 1023) / 1024;

  hipMemsetAsync(deg, 0, (size_t)N * 4, stream);
  k_deg<<<(E + 255) / 256, 256, 0, stream>>>(dstp, E, deg);
  k_scan1<<<nb, 1024, 0, stream>>>(deg, excl, partials, dinv, N);
  k_scan2<<<1, 1024, 0, stream>>>(partials, nb, rowptr, N);
  k_scan3<<<(N + 255) / 256, 256, 0, stream>>>(excl, partials, rowptr, cursor, N);
  k_fill<<<(E + 255) / 256, 256, 0, stream>>>(srcp, dstp, E, cursor, csr);
  k_prepW<<<16, 256, 0, stream>>>(W1, Wt1);
  k_prepW<<<16, 256, 0, stream>>>(W2, Wt2);

  const int gblocks = (N + 63) / 64;
  // layer 1
  k_mfma_gemm<1><<<gblocks, 256, 0, stream>>>(x, Wt1, dinv, U0, N);
  k_gather_post<<<(N + 3) / 4, 256, 0, stream>>>(csr, rowptr, U0, dinv, b1, U1, N);
  // layer 2
  k_mfma_gemm<0><<<gblocks, 256, 0, stream>>>(U1, Wt2, dinv, U0, N);
  k_gather_post<<<(N + 3) / 4, 256, 0, stream>>>(csr, rowptr, U0, dinv, b2, U1, N);

  k_pool_fc<<<NG, 128, 0, stream>>>(U1, batch, N, Wf1, bf1, Wf2, bf2, out);
}

// Round 5
// 268.478 us; speedup vs baseline: 5.5336x; 1.0142x over previous
//
#include <hip/hip_runtime.h>

typedef __attribute__((ext_vector_type(8))) short short8;
typedef __attribute__((ext_vector_type(4))) float f32x4;

__device__ __forceinline__ unsigned short f2b(float x) {
  unsigned u = __float_as_uint(x);
  u += 0x7FFF + ((u >> 16) & 1);           // round-to-nearest-even
  return (unsigned short)(u >> 16);
}
__device__ __forceinline__ float b2f_lo(unsigned v) { return __uint_as_float(v << 16); }
__device__ __forceinline__ float b2f_hi(unsigned v) { return __uint_as_float(v & 0xFFFF0000u); }
__device__ __forceinline__ float b2f(unsigned short v) { return __uint_as_float(((unsigned)v) << 16); }

#define EPB 4096   // edges per partition block
#define BKT 256    // nodes per bucket

// per-block bucket histogram -> mat[blk][bucket]
__global__ __launch_bounds__(256) void k_hist(const int* __restrict__ dst, int E,
                                              int nbuck, int* __restrict__ mat) {
  __shared__ int h[256];
  int t = threadIdx.x;
  h[t] = 0;
  __syncthreads();
  int e0 = blockIdx.x * EPB, e1 = min(e0 + EPB, E);
  for (int e = e0 + t; e < e1; e += 256) atomicAdd(&h[dst[e] >> 8], 1);
  __syncthreads();
  if (t < nbuck) mat[blockIdx.x * nbuck + t] = h[t];
}

// single block: column sums -> exclusive bucket offsets; matrix -> per-(blk,bucket) bases
__global__ __launch_bounds__(256) void k_scanb(int* __restrict__ mat, int neb, int nbuck,
                                               int* __restrict__ boff,
                                               int* __restrict__ rowptr, int N_) {
  __shared__ int tot[256];
  int t = threadIdx.x;
  int sum = 0;
  if (t < nbuck)
    for (int b = 0; b < neb; ++b) sum += mat[b * nbuck + t];
  tot[t] = sum;
  __syncthreads();
  #pragma unroll
  for (int d = 1; d < 256; d <<= 1) {
    int u = (t >= d) ? tot[t - d] : 0;
    __syncthreads();
    tot[t] += u;
    __syncthreads();
  }
  int base = (t == 0) ? 0 : tot[t - 1];
  if (t < nbuck) {
    boff[t] = base;
    int run = base;
    for (int b = 0; b < neb; ++b) {
      int v = mat[b * nbuck + t];
      mat[b * nbuck + t] = run;
      run += v;
    }
  }
  if (t == 0) {
    boff[nbuck] = tot[255];      // == E
    rowptr[N_] = tot[255];
  }
}

// scatter edges into bucket-grouped staging: staged = (dst&255)<<16 | src  (uint16 each)
__global__ __launch_bounds__(256) void k_part(const int* __restrict__ src,
                                              const int* __restrict__ dst, int E, int nbuck,
                                              const int* __restrict__ mat,
                                              unsigned* __restrict__ staged) {
  __shared__ int cur[256];
  int t = threadIdx.x;
  if (t < nbuck) cur[t] = mat[blockIdx.x * nbuck + t];
  __syncthreads();
  int e0 = blockIdx.x * EPB, e1 = min(e0 + EPB, E);
  for (int e = e0 + t; e < e1; e += 256) {
    int d = dst[e];
    int pos = atomicAdd(&cur[d >> 8], 1);
    staged[pos] = ((unsigned)(d & 255) << 16) | (unsigned)src[e];
  }
}

// one block per bucket: per-node count (LDS) -> rowptr + dinv, then place csr entries (uint16)
__global__ __launch_bounds__(256) void k_csr(const unsigned* __restrict__ staged,
                                             const int* __restrict__ boff, int N_,
                                             float* __restrict__ dinv, int* __restrict__ rowptr,
                                             unsigned short* __restrict__ csr16) {
  __shared__ int cnt[256];
  __shared__ int cur[256];
  int b = blockIdx.x, t = threadIdx.x;
  int lo = boff[b], hi = boff[b + 1];
  cnt[t] = 0;
  __syncthreads();
  for (int i = lo + t; i < hi; i += 256) atomicAdd(&cnt[staged[i] >> 16], 1);
  __syncthreads();
  int v = cnt[t];
  #pragma unroll
  for (int d = 1; d < 256; d <<= 1) {
    int u = (t >= d) ? cnt[t - d] : 0;
    __syncthreads();
    cnt[t] += u;
    __syncthreads();
  }
  int start = lo + cnt[t] - v;     // exclusive within bucket
  cur[t] = start;
  int node = (b << 8) + t;
  if (node < N_) {
    rowptr[node] = start;
    dinv[node] = rsqrtf((float)(v + 1));
  }
  __syncthreads();
  for (int i = lo + t; i < hi; i += 256) {
    unsigned e = staged[i];
    int pos = atomicAdd(&cur[e >> 16], 1);
    csr16[pos] = (unsigned short)(e & 0xFFFFu);
  }
}

// cast + transpose W[128][128] f32 -> Wt[col][k] bf16
__global__ __launch_bounds__(256) void k_prepW(const float* __restrict__ W,
                                               unsigned short* __restrict__ Wt) {
  __shared__ float t[32][33];
  int tx = threadIdx.x & 31, ty = threadIdx.x >> 5;
  int bx = blockIdx.x & 3, by = blockIdx.x >> 2;
  #pragma unroll
  for (int i = 0; i < 4; ++i)
    t[ty + i * 8][tx] = W[(by * 32 + ty + i * 8) * 128 + bx * 32 + tx];
  __syncthreads();
  #pragma unroll
  for (int i = 0; i < 4; ++i)
    Wt[(bx * 32 + ty + i * 8) * 128 + by * 32 + tx] = f2b(t[tx][ty + i * 8]);
}

// Out[r][c] = bf16( (sum_k A[r][k]*W[k][c]) * dinv[r] ).  A: f32 (A_F32=1) or bf16.
template<int A_F32>
__global__ __launch_bounds__(256) void k_mfma_gemm(
    const void* __restrict__ Ap, const unsigned short* __restrict__ Wt,
    const float* __restrict__ dinv, unsigned short* __restrict__ Out, int M)
{
  int wv = threadIdx.x >> 6, lane = threadIdx.x & 63;
  int r0 = blockIdx.x * 64 + wv * 16;
  if (r0 >= M) return;
  int arow = r0 + (lane & 15);
  int kb = (lane >> 4) * 8;
  short8 a[4];
  if (A_F32) {
    const float* Ar = (const float*)Ap + (size_t)arow * 128 + kb;
    #pragma unroll
    for (int ks = 0; ks < 4; ++ks) {
      float4 u = *(const float4*)(Ar + ks * 32);
      float4 v = *(const float4*)(Ar + ks * 32 + 4);
      short8 tt;
      tt[0] = (short)f2b(u.x); tt[1] = (short)f2b(u.y);
      tt[2] = (short)f2b(u.z); tt[3] = (short)f2b(u.w);
      tt[4] = (short)f2b(v.x); tt[5] = (short)f2b(v.y);
      tt[6] = (short)f2b(v.z); tt[7] = (short)f2b(v.w);
      a[ks] = tt;
    }
  } else {
    const unsigned short* Ar = (const unsigned short*)Ap + (size_t)arow * 128 + kb;
    #pragma unroll
    for (int ks = 0; ks < 4; ++ks)
      a[ks] = *(const short8*)(Ar + ks * 32);
  }
  f32x4 acc[8];
  #pragma unroll
  for (int i = 0; i < 8; ++i) acc[i] = (f32x4){0.f, 0.f, 0.f, 0.f};
  const unsigned short* Bc = Wt + (size_t)(lane & 15) * 128 + kb;
  #pragma unroll
  for (int ct = 0; ct < 8; ++ct) {
    const unsigned short* B = Bc + ct * 16 * 128;
    #pragma unroll
    for (int ks = 0; ks < 4; ++ks)
      acc[ct] = __builtin_amdgcn_mfma_f32_16x16x32_bf16(
          a[ks], *(const short8*)(B + ks * 32), acc[ct], 0, 0, 0);
  }
  int orow = r0 + (lane >> 4) * 4;
  int ocol = lane & 15;
  float s0 = dinv[orow], s1 = dinv[orow + 1], s2 = dinv[orow + 2], s3 = dinv[orow + 3];
  #pragma unroll
  for (int ct = 0; ct < 8; ++ct) {
    unsigned short* o = Out + (size_t)orow * 128 + ct * 16 + ocol;
    o[0]   = f2b(acc[ct][0] * s0);
    o[128] = f2b(acc[ct][1] * s1);
    o[256] = f2b(acc[ct][2] * s2);
    o[384] = f2b(acc[ct][3] * s3);
  }
}

// one wave per dst node over bf16 rows: R = bf16(relu(dinv*(sum P[src] + P[dst]) + b))
__global__ __launch_bounds__(256) void k_gather_post(
    const unsigned short* __restrict__ csr16, const int* __restrict__ rowptr,
    const unsigned short* __restrict__ P, const float* __restrict__ dinv,
    const float* __restrict__ bias, unsigned short* __restrict__ R, int n)
{
  int node = blockIdx.x * 4 + (threadIdx.x >> 6);
  if (node >= n) return;
  int lane = threadIdx.x & 63;
  int lo = rowptr[node], hi = rowptr[node + 1];
  float ax = 0.f, ay = 0.f;
  #pragma unroll 4
  for (int e = lo; e < hi; ++e) {
    unsigned s = csr16[e];
    unsigned v = ((const unsigned*)(P + (size_t)s * 128))[lane];
    ax += b2f_lo(v); ay += b2f_hi(v);
  }
  float dv = dinv[node];
  unsigned hv = ((const unsigned*)(P + (size_t)node * 128))[lane];
  float2 b = ((const float2*)bias)[lane];
  float rx = fmaxf(dv * (ax + b2f_lo(hv)) + b.x, 0.f);
  float ry = fmaxf(dv * (ay + b2f_hi(hv)) + b.y, 0.f);
  unsigned pack = (unsigned)f2b(rx) | ((unsigned)f2b(ry) << 16);
  ((unsigned*)(R + (size_t)node * 128))[lane] = pack;
}

__device__ __forceinline__ int lower_bound_i(const int* a, int n, int v) {
  int lo = 0, hi = n;
  while (lo < hi) { int m = (lo + hi) >> 1; if (a[m] < v) lo = m + 1; else hi = m; }
  return lo;
}

__global__ __launch_bounds__(128) void k_pool_fc(
    const unsigned short* __restrict__ h2, const int* __restrict__ batch, int n,
    const float* __restrict__ Wf1, const float* __restrict__ bf1,
    const float* __restrict__ Wf2, const float* __restrict__ bf2,
    float* __restrict__ out)
{
  __shared__ float gl[128];
  __shared__ float zl[128];
  int g = blockIdx.x, t = threadIdx.x;
  int lo = lower_bound_i(batch, n, g);
  int hi = lower_bound_i(batch, n, g + 1);
  float acc = 0.f;
  for (int i = lo; i < hi; ++i) acc += b2f(h2[(size_t)i * 128 + t]);
  gl[t] = acc / fmaxf((float)(hi - lo), 1.f);
  __syncthreads();
  float z = bf1[t];
  #pragma unroll 16
  for (int k = 0; k < 128; ++k) z += gl[k] * Wf1[k * 128 + t];
  zl[t] = fmaxf(z, 0.f);
  __syncthreads();
  if (t < 2) {
    float o = bf2[t];
    for (int k = 0; k < 128; ++k) o += zl[k] * Wf2[k * 2 + t];
    out[g * 2 + t] = o;
  }
}

extern "C" void kernel_launch(void* const* d_in, const int* in_sizes, int n_in,
                              void* d_out, int out_size, void* d_ws, size_t ws_size,
                              hipStream_t stream) {
  const float* x    = (const float*)d_in[0];
  const int*   ei   = (const int*)d_in[1];
  const int*   batch= (const int*)d_in[2];
  const float* W1   = (const float*)d_in[3];
  const float* b1   = (const float*)d_in[4];
  const float* W2   = (const float*)d_in[5];
  const float* b2   = (const float*)d_in[6];
  const float* Wf1  = (const float*)d_in[7];
  const float* bf1  = (const float*)d_in[8];
  const float* Wf2  = (const float*)d_in[9];
  const float* bf2  = (const float*)d_in[10];
  float* out = (float*)d_out;

  const int N  = in_sizes[0] / 128;    // requires N < 65536 for uint16 csr entries
  const int E  = in_sizes[1] / 2;
  const int NG = out_size / 2;
  const int* srcp = ei;
  const int* dstp = ei + E;

  const int nbuck = (N + BKT - 1) / BKT;     // <= 256
  const int neb   = (E + EPB - 1) / EPB;

  char* ws = (char*)d_ws;
  size_t off = 0;
  auto carve = [&](size_t bytes) { void* p = ws + off; off += (bytes + 255) & ~(size_t)255; return p; };
  float* dinv   = (float*)carve((size_t)N * 4);
  int*   rowptr = (int*)  carve((size_t)(N + 1) * 4);
  int*   boff   = (int*)  carve((size_t)(nbuck + 1) * 4);
  int*   mat    = (int*)  carve((size_t)neb * nbuck * 4);
  unsigned*       staged = (unsigned*)      carve((size_t)E * 4);
  unsigned short* csr16  = (unsigned short*)carve((size_t)E * 2);
  unsigned short* Wt1 = (unsigned short*)carve(128 * 128 * 2);
  unsigned short* Wt2 = (unsigned short*)carve(128 * 128 * 2);
  const size_t nb_row = (size_t)N * 128 * 2;   // bf16 rows
  unsigned short* U0 = (unsigned short*)carve(nb_row);
  unsigned short* U1 = (unsigned short*)carve(nb_row);

  // CSR build (atomic-free, bucket-partitioned)
  k_hist <<<neb, 256, 0, stream>>>(dstp, E, nbuck, mat);
  k_scanb<<<1, 256, 0, stream>>>(mat, neb, nbuck, boff, rowptr, N);
  k_part <<<neb, 256, 0, stream>>>(srcp, dstp, E, nbuck, mat, staged);
  k_csr  <<<nbuck, 256, 0, stream>>>(staged, boff, N, dinv, rowptr, csr16);

  k_prepW<<<16, 256, 0, stream>>>(W1, Wt1);
  k_prepW<<<16, 256, 0, stream>>>(W2, Wt2);

  const int gblocks = (N + 63) / 64;
  // layer 1
  k_mfma_gemm<1><<<gblocks, 256, 0, stream>>>(x, Wt1, dinv, U0, N);
  k_gather_post<<<(N + 3) / 4, 256, 0, stream>>>(csr16, rowptr, U0, dinv, b1, U1, N);
  // layer 2
  k_mfma_gemm<0><<<gblocks, 256, 0, stream>>>(U1, Wt2, dinv, U0, N);
  k_gather_post<<<(N + 3) / 4, 256, 0, stream>>>(csr16, rowptr, U0, dinv, b2, U1, N);

  k_pool_fc<<<NG, 128, 0, stream>>>(U1, batch, N, Wf1, bf1, Wf2, bf2, out);
}

// Round 6
// 213.654 us; speedup vs baseline: 6.9535x; 1.2566x over previous
//
#include <hip/hip_runtime.h>

typedef __attribute__((ext_vector_type(8))) short short8;
typedef __attribute__((ext_vector_type(4))) float f32x4;

__device__ __forceinline__ unsigned short f2b(float x) {
  unsigned u = __float_as_uint(x);
  u += 0x7FFF + ((u >> 16) & 1);           // round-to-nearest-even
  return (unsigned short)(u >> 16);
}
__device__ __forceinline__ float b2f_lo(unsigned v) { return __uint_as_float(v << 16); }
__device__ __forceinline__ float b2f_hi(unsigned v) { return __uint_as_float(v & 0xFFFF0000u); }
__device__ __forceinline__ float b2f(unsigned short v) { return __uint_as_float(((unsigned)v) << 16); }

#define EPB 4096   // edges per partition block
#define BKT 256    // nodes per bucket

// per-block bucket histogram -> mat[blk][bucket]; global bucket totals via atomics
__global__ __launch_bounds__(256) void k_hist(const int* __restrict__ dst, int E,
                                              int nbuck, int* __restrict__ mat,
                                              int* __restrict__ tot) {
  __shared__ int h[256];
  int t = threadIdx.x;
  h[t] = 0;
  __syncthreads();
  int e0 = blockIdx.x * EPB, e1 = min(e0 + EPB, E);
  for (int e = e0 + t; e < e1; e += 256) atomicAdd(&h[dst[e] >> 8], 1);
  __syncthreads();
  if (t < nbuck) {
    mat[blockIdx.x * nbuck + t] = h[t];
    if (h[t]) atomicAdd(&tot[t], h[t]);
  }
}

// one small block: exclusive scan of 256 bucket totals -> boff; rowptr[N]=E
__global__ __launch_bounds__(256) void k_excl(const int* __restrict__ tot, int nbuck,
                                              int* __restrict__ boff,
                                              int* __restrict__ rowptr, int N_) {
  __shared__ int s[256];
  int t = threadIdx.x;
  int v = (t < nbuck) ? tot[t] : 0;
  s[t] = v;
  __syncthreads();
  #pragma unroll
  for (int d = 1; d < 256; d <<= 1) {
    int u = (t >= d) ? s[t - d] : 0;
    __syncthreads();
    s[t] += u;
    __syncthreads();
  }
  if (t < nbuck) boff[t] = s[t] - v;
  if (t == 0) { boff[nbuck] = s[255]; rowptr[N_] = s[255]; }
}

// one block per bucket: exclusive scan down column -> per-(blk,bucket) write bases
__global__ __launch_bounds__(256) void k_colscan(int* __restrict__ mat, int neb, int nbuck,
                                                 const int* __restrict__ boff) {
  __shared__ int s[256];
  int b = blockIdx.x, t = threadIdx.x;
  int v = (t < neb) ? mat[t * nbuck + b] : 0;
  s[t] = v;
  __syncthreads();
  #pragma unroll
  for (int d = 1; d < 256; d <<= 1) {
    int u = (t >= d) ? s[t - d] : 0;
    __syncthreads();
    s[t] += u;
    __syncthreads();
  }
  if (t < neb) mat[t * nbuck + b] = boff[b] + s[t] - v;
}

// scatter edges into bucket-grouped staging: staged = (dst&255)<<16 | src  (uint16 each)
__global__ __launch_bounds__(256) void k_part(const int* __restrict__ src,
                                              const int* __restrict__ dst, int E, int nbuck,
                                              const int* __restrict__ mat,
                                              unsigned* __restrict__ staged) {
  __shared__ int cur[256];
  int t = threadIdx.x;
  if (t < nbuck) cur[t] = mat[blockIdx.x * nbuck + t];
  __syncthreads();
  int e0 = blockIdx.x * EPB, e1 = min(e0 + EPB, E);
  for (int e = e0 + t; e < e1; e += 256) {
    int d = dst[e];
    int pos = atomicAdd(&cur[d >> 8], 1);
    staged[pos] = ((unsigned)(d & 255) << 16) | (unsigned)src[e];
  }
}

// one block per bucket: per-node count (LDS) -> rowptr + dinv, then place csr entries (uint16)
__global__ __launch_bounds__(256) void k_csr(const unsigned* __restrict__ staged,
                                             const int* __restrict__ boff, int N_,
                                             float* __restrict__ dinv, int* __restrict__ rowptr,
                                             unsigned short* __restrict__ csr16) {
  __shared__ int cnt[256];
  __shared__ int cur[256];
  int b = blockIdx.x, t = threadIdx.x;
  int lo = boff[b], hi = boff[b + 1];
  cnt[t] = 0;
  __syncthreads();
  for (int i = lo + t; i < hi; i += 256) atomicAdd(&cnt[staged[i] >> 16], 1);
  __syncthreads();
  int v = cnt[t];
  #pragma unroll
  for (int d = 1; d < 256; d <<= 1) {
    int u = (t >= d) ? cnt[t - d] : 0;
    __syncthreads();
    cnt[t] += u;
    __syncthreads();
  }
  int start = lo + cnt[t] - v;     // exclusive within bucket
  cur[t] = start;
  int node = (b << 8) + t;
  if (node < N_) {
    rowptr[node] = start;
    dinv[node] = rsqrtf((float)(v + 1));
  }
  __syncthreads();
  for (int i = lo + t; i < hi; i += 256) {
    unsigned e = staged[i];
    int pos = atomicAdd(&cur[e >> 16], 1);
    csr16[pos] = (unsigned short)(e & 0xFFFFu);
  }
}

// cast + transpose W[128][128] f32 -> Wt[col][k] bf16
__global__ __launch_bounds__(256) void k_prepW(const float* __restrict__ W,
                                               unsigned short* __restrict__ Wt) {
  __shared__ float t[32][33];
  int tx = threadIdx.x & 31, ty = threadIdx.x >> 5;
  int bx = blockIdx.x & 3, by = blockIdx.x >> 2;
  #pragma unroll
  for (int i = 0; i < 4; ++i)
    t[ty + i * 8][tx] = W[(by * 32 + ty + i * 8) * 128 + bx * 32 + tx];
  __syncthreads();
  #pragma unroll
  for (int i = 0; i < 4; ++i)
    Wt[(bx * 32 + ty + i * 8) * 128 + by * 32 + tx] = f2b(t[tx][ty + i * 8]);
}

// Out[r][c] = bf16( (sum_k A[r][k]*W[k][c]) * dinv[r] ).  A: f32 (A_F32=1) or bf16.
template<int A_F32>
__global__ __launch_bounds__(256) void k_mfma_gemm(
    const void* __restrict__ Ap, const unsigned short* __restrict__ Wt,
    const float* __restrict__ dinv, unsigned short* __restrict__ Out, int M)
{
  int wv = threadIdx.x >> 6, lane = threadIdx.x & 63;
  int r0 = blockIdx.x * 64 + wv * 16;
  if (r0 >= M) return;
  int arow = r0 + (lane & 15);
  int kb = (lane >> 4) * 8;
  short8 a[4];
  if (A_F32) {
    const float* Ar = (const float*)Ap + (size_t)arow * 128 + kb;
    #pragma unroll
    for (int ks = 0; ks < 4; ++ks) {
      float4 u = *(const float4*)(Ar + ks * 32);
      float4 v = *(const float4*)(Ar + ks * 32 + 4);
      short8 tt;
      tt[0] = (short)f2b(u.x); tt[1] = (short)f2b(u.y);
      tt[2] = (short)f2b(u.z); tt[3] = (short)f2b(u.w);
      tt[4] = (short)f2b(v.x); tt[5] = (short)f2b(v.y);
      tt[6] = (short)f2b(v.z); tt[7] = (short)f2b(v.w);
      a[ks] = tt;
    }
  } else {
    const unsigned short* Ar = (const unsigned short*)Ap + (size_t)arow * 128 + kb;
    #pragma unroll
    for (int ks = 0; ks < 4; ++ks)
      a[ks] = *(const short8*)(Ar + ks * 32);
  }
  f32x4 acc[8];
  #pragma unroll
  for (int i = 0; i < 8; ++i) acc[i] = (f32x4){0.f, 0.f, 0.f, 0.f};
  const unsigned short* Bc = Wt + (size_t)(lane & 15) * 128 + kb;
  #pragma unroll
  for (int ct = 0; ct < 8; ++ct) {
    const unsigned short* B = Bc + ct * 16 * 128;
    #pragma unroll
    for (int ks = 0; ks < 4; ++ks)
      acc[ct] = __builtin_amdgcn_mfma_f32_16x16x32_bf16(
          a[ks], *(const short8*)(B + ks * 32), acc[ct], 0, 0, 0);
  }
  int orow = r0 + (lane >> 4) * 4;
  int ocol = lane & 15;
  float s0 = dinv[orow], s1 = dinv[orow + 1], s2 = dinv[orow + 2], s3 = dinv[orow + 3];
  #pragma unroll
  for (int ct = 0; ct < 8; ++ct) {
    unsigned short* o = Out + (size_t)orow * 128 + ct * 16 + ocol;
    o[0]   = f2b(acc[ct][0] * s0);
    o[128] = f2b(acc[ct][1] * s1);
    o[256] = f2b(acc[ct][2] * s2);
    o[384] = f2b(acc[ct][3] * s3);
  }
}

// one wave per dst node over bf16 rows: R = bf16(relu(dinv*(sum P[src] + P[dst]) + b))
__global__ __launch_bounds__(256) void k_gather_post(
    const unsigned short* __restrict__ csr16, const int* __restrict__ rowptr,
    const unsigned short* __restrict__ P, const float* __restrict__ dinv,
    const float* __restrict__ bias, unsigned short* __restrict__ R, int n)
{
  int node = blockIdx.x * 4 + (threadIdx.x >> 6);
  if (node >= n) return;
  int lane = threadIdx.x & 63;
  int lo = rowptr[node], hi = rowptr[node + 1];
  float ax = 0.f, ay = 0.f;
  #pragma unroll 4
  for (int e = lo; e < hi; ++e) {
    unsigned s = csr16[e];
    unsigned v = ((const unsigned*)(P + (size_t)s * 128))[lane];
    ax += b2f_lo(v); ay += b2f_hi(v);
  }
  float dv = dinv[node];
  unsigned hv = ((const unsigned*)(P + (size_t)node * 128))[lane];
  float2 b = ((const float2*)bias)[lane];
  float rx = fmaxf(dv * (ax + b2f_lo(hv)) + b.x, 0.f);
  float ry = fmaxf(dv * (ay + b2f_hi(hv)) + b.y, 0.f);
  unsigned pack = (unsigned)f2b(rx) | ((unsigned)f2b(ry) << 16);
  ((unsigned*)(R + (size_t)node * 128))[lane] = pack;
}

__device__ __forceinline__ int lower_bound_i(const int* a, int n, int v) {
  int lo = 0, hi = n;
  while (lo < hi) { int m = (lo + hi) >> 1; if (a[m] < v) lo = m + 1; else hi = m; }
  return lo;
}

__global__ __launch_bounds__(128) void k_pool_fc(
    const unsigned short* __restrict__ h2, const int* __restrict__ batch, int n,
    const float* __restrict__ Wf1, const float* __restrict__ bf1,
    const float* __restrict__ Wf2, const float* __restrict__ bf2,
    float* __restrict__ out)
{
  __shared__ float gl[128];
  __shared__ float zl[128];
  int g = blockIdx.x, t = threadIdx.x;
  int lo = lower_bound_i(batch, n, g);
  int hi = lower_bound_i(batch, n, g + 1);
  float acc = 0.f;
  for (int i = lo; i < hi; ++i) acc += b2f(h2[(size_t)i * 128 + t]);
  gl[t] = acc / fmaxf((float)(hi - lo), 1.f);
  __syncthreads();
  float z = bf1[t];
  #pragma unroll 16
  for (int k = 0; k < 128; ++k) z += gl[k] * Wf1[k * 128 + t];
  zl[t] = fmaxf(z, 0.f);
  __syncthreads();
  if (t < 2) {
    float o = bf2[t];
    for (int k = 0; k < 128; ++k) o += zl[k] * Wf2[k * 2 + t];
    out[g * 2 + t] = o;
  }
}

extern "C" void kernel_launch(void* const* d_in, const int* in_sizes, int n_in,
                              void* d_out, int out_size, void* d_ws, size_t ws_size,
                              hipStream_t stream) {
  const float* x    = (const float*)d_in[0];
  const int*   ei   = (const int*)d_in[1];
  const int*   batch= (const int*)d_in[2];
  const float* W1   = (const float*)d_in[3];
  const float* b1   = (const float*)d_in[4];
  const float* W2   = (const float*)d_in[5];
  const float* b2   = (const float*)d_in[6];
  const float* Wf1  = (const float*)d_in[7];
  const float* bf1  = (const float*)d_in[8];
  const float* Wf2  = (const float*)d_in[9];
  const float* bf2  = (const float*)d_in[10];
  float* out = (float*)d_out;

  const int N  = in_sizes[0] / 128;    // requires N < 65536 for uint16 csr entries
  const int E  = in_sizes[1] / 2;
  const int NG = out_size / 2;
  const int* srcp = ei;
  const int* dstp = ei + E;

  const int nbuck = (N + BKT - 1) / BKT;     // <= 256
  const int neb   = (E + EPB - 1) / EPB;     // <= 256

  char* ws = (char*)d_ws;
  size_t off = 0;
  auto carve = [&](size_t bytes) { void* p = ws + off; off += (bytes + 255) & ~(size_t)255; return p; };
  float* dinv   = (float*)carve((size_t)N * 4);
  int*   rowptr = (int*)  carve((size_t)(N + 1) * 4);
  int*   boff   = (int*)  carve((size_t)(nbuck + 1) * 4);
  int*   tot    = (int*)  carve((size_t)256 * 4);
  int*   mat    = (int*)  carve((size_t)neb * nbuck * 4);
  unsigned*       staged = (unsigned*)      carve((size_t)E * 4);
  unsigned short* csr16  = (unsigned short*)carve((size_t)E * 2);
  unsigned short* Wt1 = (unsigned short*)carve(128 * 128 * 2);
  unsigned short* Wt2 = (unsigned short*)carve(128 * 128 * 2);
  const size_t nb_row = (size_t)N * 128 * 2;   // bf16 rows
  unsigned short* U0 = (unsigned short*)carve(nb_row);
  unsigned short* U1 = (unsigned short*)carve(nb_row);

  // CSR build (atomic-free placement, bucket-partitioned, parallel offsets)
  hipMemsetAsync(tot, 0, 256 * 4, stream);
  k_hist   <<<neb, 256, 0, stream>>>(dstp, E, nbuck, mat, tot);
  k_excl   <<<1, 256, 0, stream>>>(tot, nbuck, boff, rowptr, N);
  k_colscan<<<nbuck, 256, 0, stream>>>(mat, neb, nbuck, boff);
  k_part   <<<neb, 256, 0, stream>>>(srcp, dstp, E, nbuck, mat, staged);
  k_csr    <<<nbuck, 256, 0, stream>>>(staged, boff, N, dinv, rowptr, csr16);

  k_prepW<<<16, 256, 0, stream>>>(W1, Wt1);
  k_prepW<<<16, 256, 0, stream>>>(W2, Wt2);

  const int gblocks = (N + 63) / 64;
  // layer 1
  k_mfma_gemm<1><<<gblocks, 256, 0, stream>>>(x, Wt1, dinv, U0, N);
  k_gather_post<<<(N + 3) / 4, 256, 0, stream>>>(csr16, rowptr, U0, dinv, b1, U1, N);
  // layer 2
  k_mfma_gemm<0><<<gblocks, 256, 0, stream>>>(U1, Wt2, dinv, U0, N);
  k_gather_post<<<(N + 3) / 4, 256, 0, stream>>>(csr16, rowptr, U0, dinv, b2, U1, N);

  k_pool_fc<<<NG, 128, 0, stream>>>(U1, batch, N, Wf1, bf1, Wf2, bf2, out);
}

// Round 7
// 190.019 us; speedup vs baseline: 7.8184x; 1.1244x over previous
//
#include <hip/hip_runtime.h>

typedef __attribute__((ext_vector_type(8))) short short8;
typedef __attribute__((ext_vector_type(4))) float f32x4;

__device__ __forceinline__ unsigned short f2b(float x) {
  unsigned u = __float_as_uint(x);
  u += 0x7FFF + ((u >> 16) & 1);           // round-to-nearest-even
  return (unsigned short)(u >> 16);
}
__device__ __forceinline__ float b2f_lo(unsigned v) { return __uint_as_float(v << 16); }
__device__ __forceinline__ float b2f_hi(unsigned v) { return __uint_as_float(v & 0xFFFF0000u); }

#define EPB 4096   // edges per partition block
#define BKT 256    // nodes per bucket
#define RPW 32     // rows per wave in pooling

// per-block bucket histogram -> mat[blk][bucket]; bucket totals via atomics (tot pre-zeroed)
__global__ __launch_bounds__(256) void k_hist(const int* __restrict__ dst, int E,
                                              int nbuck, int* __restrict__ mat,
                                              int* __restrict__ tot) {
  __shared__ int h[256];
  int t = threadIdx.x;
  h[t] = 0;
  __syncthreads();
  int e0 = blockIdx.x * EPB, e1 = min(e0 + EPB, E);
  for (int e = e0 + t; e < e1; e += 256) atomicAdd(&h[dst[e] >> 8], 1);
  __syncthreads();
  if (t < nbuck) {
    mat[blockIdx.x * nbuck + t] = h[t];
    if (h[t]) atomicAdd(&tot[t], h[t]);
  }
}

// one small block: exclusive scan of 256 bucket totals -> boff; rowptr[N]=E
__global__ __launch_bounds__(256) void k_excl(const int* __restrict__ tot, int nbuck,
                                              int* __restrict__ boff,
                                              int* __restrict__ rowptr, int N_) {
  __shared__ int s[256];
  int t = threadIdx.x;
  int v = (t < nbuck) ? tot[t] : 0;
  s[t] = v;
  __syncthreads();
  #pragma unroll
  for (int d = 1; d < 256; d <<= 1) {
    int u = (t >= d) ? s[t - d] : 0;
    __syncthreads();
    s[t] += u;
    __syncthreads();
  }
  if (t < nbuck) boff[t] = s[t] - v;
  if (t == 0) { boff[nbuck] = s[255]; rowptr[N_] = s[255]; }
}

// one block per bucket: exclusive scan down column -> per-(blk,bucket) write bases.
// Also zeroes the pooling buffers (sums NG*128 f32, cnt NG ints) for later use.
__global__ __launch_bounds__(256) void k_colscan(int* __restrict__ mat, int neb, int nbuck,
                                                 const int* __restrict__ boff,
                                                 float* __restrict__ sums,
                                                 int* __restrict__ cnt, int ng) {
  __shared__ int s[256];
  int b = blockIdx.x, t = threadIdx.x;
  int v = (t < neb) ? mat[t * nbuck + b] : 0;
  s[t] = v;
  __syncthreads();
  #pragma unroll
  for (int d = 1; d < 256; d <<= 1) {
    int u = (t >= d) ? s[t - d] : 0;
    __syncthreads();
    s[t] += u;
    __syncthreads();
  }
  if (t < neb) mat[t * nbuck + b] = boff[b] + s[t] - v;
  int tot_e = ng * 128;
  for (int i = b * 256 + t; i < tot_e; i += gridDim.x * 256) sums[i] = 0.f;
  for (int i = b * 256 + t; i < ng; i += gridDim.x * 256) cnt[i] = 0;
}

// scatter edges into bucket-grouped staging: staged = (dst&255)<<16 | src  (uint16 each)
__global__ __launch_bounds__(256) void k_part(const int* __restrict__ src,
                                              const int* __restrict__ dst, int E, int nbuck,
                                              const int* __restrict__ mat,
                                              unsigned* __restrict__ staged) {
  __shared__ int cur[256];
  int t = threadIdx.x;
  if (t < nbuck) cur[t] = mat[blockIdx.x * nbuck + t];
  __syncthreads();
  int e0 = blockIdx.x * EPB, e1 = min(e0 + EPB, E);
  for (int e = e0 + t; e < e1; e += 256) {
    int d = dst[e];
    int pos = atomicAdd(&cur[d >> 8], 1);
    staged[pos] = ((unsigned)(d & 255) << 16) | (unsigned)src[e];
  }
}

// one block per bucket: per-node count (LDS) -> rowptr + dinv, then place csr entries (uint16)
__global__ __launch_bounds__(256) void k_csr(const unsigned* __restrict__ staged,
                                             const int* __restrict__ boff, int N_,
                                             float* __restrict__ dinv, int* __restrict__ rowptr,
                                             unsigned short* __restrict__ csr16) {
  __shared__ int cnt[256];
  __shared__ int cur[256];
  int b = blockIdx.x, t = threadIdx.x;
  int lo = boff[b], hi = boff[b + 1];
  cnt[t] = 0;
  __syncthreads();
  for (int i = lo + t; i < hi; i += 256) atomicAdd(&cnt[staged[i] >> 16], 1);
  __syncthreads();
  int v = cnt[t];
  #pragma unroll
  for (int d = 1; d < 256; d <<= 1) {
    int u = (t >= d) ? cnt[t - d] : 0;
    __syncthreads();
    cnt[t] += u;
    __syncthreads();
  }
  int start = lo + cnt[t] - v;     // exclusive within bucket
  cur[t] = start;
  int node = (b << 8) + t;
  if (node < N_) {
    rowptr[node] = start;
    dinv[node] = rsqrtf((float)(v + 1));
  }
  __syncthreads();
  for (int i = lo + t; i < hi; i += 256) {
    unsigned e = staged[i];
    int pos = atomicAdd(&cur[e >> 16], 1);
    csr16[pos] = (unsigned short)(e & 0xFFFFu);
  }
}

// cast + transpose W[128][128] f32 -> Wt[col][k] bf16; optionally zero tot[256]
__global__ __launch_bounds__(256) void k_prepW(const float* __restrict__ W,
                                               unsigned short* __restrict__ Wt,
                                               int* __restrict__ tot_zero) {
  __shared__ float t[32][33];
  int tx = threadIdx.x & 31, ty = threadIdx.x >> 5;
  int bx = blockIdx.x & 3, by = blockIdx.x >> 2;
  if (tot_zero && blockIdx.x == 0) tot_zero[threadIdx.x] = 0;
  #pragma unroll
  for (int i = 0; i < 4; ++i)
    t[ty + i * 8][tx] = W[(by * 32 + ty + i * 8) * 128 + bx * 32 + tx];
  __syncthreads();
  #pragma unroll
  for (int i = 0; i < 4; ++i)
    Wt[(bx * 32 + ty + i * 8) * 128 + by * 32 + tx] = f2b(t[tx][ty + i * 8]);
}

// Out[r][c] = bf16( (sum_k A[r][k]*W[k][c]) * dinv[r] ).  A: f32 (A_F32=1) or bf16.
template<int A_F32>
__global__ __launch_bounds__(256) void k_mfma_gemm(
    const void* __restrict__ Ap, const unsigned short* __restrict__ Wt,
    const float* __restrict__ dinv, unsigned short* __restrict__ Out, int M)
{
  int wv = threadIdx.x >> 6, lane = threadIdx.x & 63;
  int r0 = blockIdx.x * 64 + wv * 16;
  if (r0 >= M) return;
  int arow = r0 + (lane & 15);
  int kb = (lane >> 4) * 8;
  short8 a[4];
  if (A_F32) {
    const float* Ar = (const float*)Ap + (size_t)arow * 128 + kb;
    #pragma unroll
    for (int ks = 0; ks < 4; ++ks) {
      float4 u = *(const float4*)(Ar + ks * 32);
      float4 v = *(const float4*)(Ar + ks * 32 + 4);
      short8 tt;
      tt[0] = (short)f2b(u.x); tt[1] = (short)f2b(u.y);
      tt[2] = (short)f2b(u.z); tt[3] = (short)f2b(u.w);
      tt[4] = (short)f2b(v.x); tt[5] = (short)f2b(v.y);
      tt[6] = (short)f2b(v.z); tt[7] = (short)f2b(v.w);
      a[ks] = tt;
    }
  } else {
    const unsigned short* Ar = (const unsigned short*)Ap + (size_t)arow * 128 + kb;
    #pragma unroll
    for (int ks = 0; ks < 4; ++ks)
      a[ks] = *(const short8*)(Ar + ks * 32);
  }
  f32x4 acc[8];
  #pragma unroll
  for (int i = 0; i < 8; ++i) acc[i] = (f32x4){0.f, 0.f, 0.f, 0.f};
  const unsigned short* Bc = Wt + (size_t)(lane & 15) * 128 + kb;
  #pragma unroll
  for (int ct = 0; ct < 8; ++ct) {
    const unsigned short* B = Bc + ct * 16 * 128;
    #pragma unroll
    for (int ks = 0; ks < 4; ++ks)
      acc[ct] = __builtin_amdgcn_mfma_f32_16x16x32_bf16(
          a[ks], *(const short8*)(B + ks * 32), acc[ct], 0, 0, 0);
  }
  int orow = r0 + (lane >> 4) * 4;
  int ocol = lane & 15;
  float s0 = dinv[orow], s1 = dinv[orow + 1], s2 = dinv[orow + 2], s3 = dinv[orow + 3];
  #pragma unroll
  for (int ct = 0; ct < 8; ++ct) {
    unsigned short* o = Out + (size_t)orow * 128 + ct * 16 + ocol;
    o[0]   = f2b(acc[ct][0] * s0);
    o[128] = f2b(acc[ct][1] * s1);
    o[256] = f2b(acc[ct][2] * s2);
    o[384] = f2b(acc[ct][3] * s3);
  }
}

// one wave per dst node over bf16 rows: R = bf16(relu(dinv*(sum P[src] + P[dst]) + b))
__global__ __launch_bounds__(256) void k_gather_post(
    const unsigned short* __restrict__ csr16, const int* __restrict__ rowptr,
    const unsigned short* __restrict__ P, const float* __restrict__ dinv,
    const float* __restrict__ bias, unsigned short* __restrict__ R, int n)
{
  int node = blockIdx.x * 4 + (threadIdx.x >> 6);
  if (node >= n) return;
  int lane = threadIdx.x & 63;
  int lo = rowptr[node], hi = rowptr[node + 1];
  float ax = 0.f, ay = 0.f;
  #pragma unroll 4
  for (int e = lo; e < hi; ++e) {
    unsigned s = csr16[e];
    unsigned v = ((const unsigned*)(P + (size_t)s * 128))[lane];
    ax += b2f_lo(v); ay += b2f_hi(v);
  }
  float dv = dinv[node];
  unsigned hv = ((const unsigned*)(P + (size_t)node * 128))[lane];
  float2 b = ((const float2*)bias)[lane];
  float rx = fmaxf(dv * (ax + b2f_lo(hv)) + b.x, 0.f);
  float ry = fmaxf(dv * (ay + b2f_hi(hv)) + b.y, 0.f);
  unsigned pack = (unsigned)f2b(rx) | ((unsigned)f2b(ry) << 16);
  ((unsigned*)(R + (size_t)node * 128))[lane] = pack;
}

// segmented mean-pool partial sums: each wave owns RPW contiguous rows (batch sorted),
// flushes per-graph register accumulators to sums/cnt at graph boundaries
__global__ __launch_bounds__(256) void k_pool_sum(
    const unsigned short* __restrict__ h2, const int* __restrict__ batch, int n,
    float* __restrict__ sums, int* __restrict__ cnt)
{
  int wid = blockIdx.x * 4 + (threadIdx.x >> 6);
  int lane = threadIdx.x & 63;
  int r0 = wid * RPW;
  if (r0 >= n) return;
  int r1 = min(r0 + RPW, n);
  const unsigned* H = (const unsigned*)h2;
  int gcur = batch[r0];
  float ax = 0.f, ay = 0.f;
  int run = 0;
  for (int r = r0; r < r1; ++r) {
    int g = batch[r];
    if (g != gcur) {
      atomicAdd(&sums[(size_t)gcur * 128 + 2 * lane], ax);
      atomicAdd(&sums[(size_t)gcur * 128 + 2 * lane + 1], ay);
      if (lane == 0) atomicAdd(&cnt[gcur], run);
      ax = ay = 0.f; run = 0; gcur = g;
    }
    unsigned v = H[(size_t)r * 64 + lane];
    ax += b2f_lo(v); ay += b2f_hi(v); ++run;
  }
  atomicAdd(&sums[(size_t)gcur * 128 + 2 * lane], ax);
  atomicAdd(&sums[(size_t)gcur * 128 + 2 * lane + 1], ay);
  if (lane == 0) atomicAdd(&cnt[gcur], run);
}

// per-graph MLP head: 4-chain ILP FC1, LDS-tree FC2
__global__ __launch_bounds__(128) void k_fc(
    const float* __restrict__ sums, const int* __restrict__ cnt,
    const float* __restrict__ Wf1, const float* __restrict__ bf1,
    const float* __restrict__ Wf2, const float* __restrict__ bf2,
    float* __restrict__ out)
{
  __shared__ float gl[128];
  __shared__ float red0[128];
  __shared__ float red1[128];
  int g = blockIdx.x, t = threadIdx.x;
  float c = (float)cnt[g];
  gl[t] = sums[(size_t)g * 128 + t] / fmaxf(c, 1.f);
  __syncthreads();
  float z0 = 0.f, z1 = 0.f, z2 = 0.f, z3 = 0.f;
  #pragma unroll
  for (int k = 0; k < 32; ++k) {
    z0 += gl[k]      * Wf1[k * 128 + t];
    z1 += gl[k + 32] * Wf1[(k + 32) * 128 + t];
    z2 += gl[k + 64] * Wf1[(k + 64) * 128 + t];
    z3 += gl[k + 96] * Wf1[(k + 96) * 128 + t];
  }
  float z = fmaxf((z0 + z1) + (z2 + z3) + bf1[t], 0.f);
  red0[t] = z * Wf2[2 * t];
  red1[t] = z * Wf2[2 * t + 1];
  __syncthreads();
  #pragma unroll
  for (int d = 64; d > 0; d >>= 1) {
    if (t < d) { red0[t] += red0[t + d]; red1[t] += red1[t + d]; }
    __syncthreads();
  }
  if (t == 0) {
    out[g * 2]     = red0[0] + bf2[0];
    out[g * 2 + 1] = red1[0] + bf2[1];
  }
}

extern "C" void kernel_launch(void* const* d_in, const int* in_sizes, int n_in,
                              void* d_out, int out_size, void* d_ws, size_t ws_size,
                              hipStream_t stream) {
  const float* x    = (const float*)d_in[0];
  const int*   ei   = (const int*)d_in[1];
  const int*   batch= (const int*)d_in[2];
  const float* W1   = (const float*)d_in[3];
  const float* b1   = (const float*)d_in[4];
  const float* W2   = (const float*)d_in[5];
  const float* b2   = (const float*)d_in[6];
  const float* Wf1  = (const float*)d_in[7];
  const float* bf1  = (const float*)d_in[8];
  const float* Wf2  = (const float*)d_in[9];
  const float* bf2  = (const float*)d_in[10];
  float* out = (float*)d_out;

  const int N  = in_sizes[0] / 128;    // requires N < 65536 for uint16 csr entries
  const int E  = in_sizes[1] / 2;
  const int NG = out_size / 2;
  const int* srcp = ei;
  const int* dstp = ei + E;

  const int nbuck = (N + BKT - 1) / BKT;     // <= 256
  const int neb   = (E + EPB - 1) / EPB;     // <= 256

  char* ws = (char*)d_ws;
  size_t off = 0;
  auto carve = [&](size_t bytes) { void* p = ws + off; off += (bytes + 255) & ~(size_t)255; return p; };
  float* dinv   = (float*)carve((size_t)N * 4);
  int*   rowptr = (int*)  carve((size_t)(N + 1) * 4);
  int*   boff   = (int*)  carve((size_t)(nbuck + 1) * 4);
  int*   tot    = (int*)  carve((size_t)256 * 4);
  int*   mat    = (int*)  carve((size_t)neb * nbuck * 4);
  unsigned*       staged = (unsigned*)      carve((size_t)E * 4);
  unsigned short* csr16  = (unsigned short*)carve((size_t)E * 2);
  unsigned short* Wt1 = (unsigned short*)carve(128 * 128 * 2);
  unsigned short* Wt2 = (unsigned short*)carve(128 * 128 * 2);
  float* sums   = (float*)carve((size_t)NG * 128 * 4);
  int*   cntg   = (int*)  carve((size_t)NG * 4);
  const size_t nb_row = (size_t)N * 128 * 2;   // bf16 rows
  unsigned short* U0 = (unsigned short*)carve(nb_row);
  unsigned short* U1 = (unsigned short*)carve(nb_row);

  // weight prep (block 0 of first call also zeroes tot)
  k_prepW<<<16, 256, 0, stream>>>(W1, Wt1, tot);
  k_prepW<<<16, 256, 0, stream>>>(W2, Wt2, nullptr);

  // CSR build (atomic-free placement, bucket-partitioned, parallel offsets)
  k_hist   <<<neb, 256, 0, stream>>>(dstp, E, nbuck, mat, tot);
  k_excl   <<<1, 256, 0, stream>>>(tot, nbuck, boff, rowptr, N);
  k_colscan<<<nbuck, 256, 0, stream>>>(mat, neb, nbuck, boff, sums, cntg, NG);
  k_part   <<<neb, 256, 0, stream>>>(srcp, dstp, E, nbuck, mat, staged);
  k_csr    <<<nbuck, 256, 0, stream>>>(staged, boff, N, dinv, rowptr, csr16);

  const int gblocks = (N + 63) / 64;
  // layer 1
  k_mfma_gemm<1><<<gblocks, 256, 0, stream>>>(x, Wt1, dinv, U0, N);
  k_gather_post<<<(N + 3) / 4, 256, 0, stream>>>(csr16, rowptr, U0, dinv, b1, U1, N);
  // layer 2
  k_mfma_gemm<0><<<gblocks, 256, 0, stream>>>(U1, Wt2, dinv, U0, N);
  k_gather_post<<<(N + 3) / 4, 256, 0, stream>>>(csr16, rowptr, U0, dinv, b2, U1, N);

  // pooling + MLP head
  const int pblocks = (N + RPW * 4 - 1) / (RPW * 4);
  k_pool_sum<<<pblocks, 256, 0, stream>>>(U1, batch, N, sums, cntg);
  k_fc<<<NG, 128, 0, stream>>>(sums, cntg, Wf1, bf1, Wf2, bf2, out);
}